// Round 2
// baseline (528.698 us; speedup 1.0000x reference)
//
#include <hip/hip_runtime.h>

typedef __attribute__((ext_vector_type(8))) short short8;
typedef __attribute__((ext_vector_type(4))) float f32x4;

#define NH 16
#define HD 80
#define SH (NH*HD)
#define WIN 64

__device__ __forceinline__ unsigned short f2bf(float x) {
    union { float f; unsigned int u; } c; c.f = x;
    unsigned int u = c.u;
    u = (u + 0x7FFFu + ((u >> 16) & 1u)) >> 16;
    return (unsigned short)u;
}
__device__ __forceinline__ float bf2f(unsigned short h) {
    union { unsigned int u; float f; } c; c.u = ((unsigned int)h) << 16;
    return c.f;
}

__global__ __launch_bounds__(256, 2) void win_attn(
    const float* __restrict__ q, const float* __restrict__ k,
    const float* __restrict__ v, const float* __restrict__ cosb,
    const float* __restrict__ sinb, float* __restrict__ out)
{
    // Q/K stored RoPE'd, bf16 hi/lo split, d padded to 96 (zeros), stride 104
    __shared__ unsigned short Qh[64*104];
    __shared__ unsigned short Ql[64*104];
    __shared__ unsigned short Kh[64*104];
    __shared__ unsigned short Kl[64*104];
    __shared__ unsigned short Vt[80*72];   // V transposed: [d][key], stride 72
    __shared__ unsigned short Ps[64*72];   // softmax probs bf16, stride 72

    const int head = blockIdx.x & (NH - 1);
    const int win  = blockIdx.x >> 4;
    const int tid  = threadIdx.x;
    const int tok0 = win * WIN;

    // ---- Phase A: load + RoPE Q,K -> LDS (hi/lo bf16) ----
    for (int idx = tid; idx < 640; idx += 256) {
        const int row = idx / 10;
        const int c0  = (idx % 10) * 4;          // column of first half (0..36)
        const size_t goff = (size_t)(tok0 + row) * SH + head * HD + c0;
        const float4 qa = *(const float4*)(q + goff);
        const float4 qb = *(const float4*)(q + goff + 40);
        const float4 ka = *(const float4*)(k + goff);
        const float4 kb = *(const float4*)(k + goff + 40);
        const size_t coff = (size_t)(tok0 + row) * 40 + c0;
        const float4 cc = *(const float4*)(cosb + coff);
        const float4 ss = *(const float4*)(sinb + coff);
        const int o0 = row * 104 + c0;
        #pragma unroll
        for (int i = 0; i < 4; ++i) {
            const float ci = ((const float*)&cc)[i], si = ((const float*)&ss)[i];
            const float q0 = ((const float*)&qa)[i], q1 = ((const float*)&qb)[i];
            const float k0 = ((const float*)&ka)[i], k1 = ((const float*)&kb)[i];
            const float qr0 = q0 * ci - q1 * si, qr1 = q0 * si + q1 * ci;
            const float kr0 = k0 * ci - k1 * si, kr1 = k0 * si + k1 * ci;
            unsigned short h;
            h = f2bf(qr0); Qh[o0 + i]      = h; Ql[o0 + i]      = f2bf(qr0 - bf2f(h));
            h = f2bf(qr1); Qh[o0 + 40 + i] = h; Ql[o0 + 40 + i] = f2bf(qr1 - bf2f(h));
            h = f2bf(kr0); Kh[o0 + i]      = h; Kl[o0 + i]      = f2bf(kr0 - bf2f(h));
            h = f2bf(kr1); Kh[o0 + 40 + i] = h; Kl[o0 + 40 + i] = f2bf(kr1 - bf2f(h));
        }
    }
    // zero-pad d in [80,96)
    for (int idx = tid; idx < 1024; idx += 256) {
        const int o = (idx >> 4) * 104 + 80 + (idx & 15);
        Qh[o] = 0; Ql[o] = 0; Kh[o] = 0; Kl[o] = 0;
    }
    // V -> LDS transposed bf16
    for (int idx = tid; idx < 1280; idx += 256) {
        const int row = idx / 20;
        const int c   = (idx % 20) * 4;
        const float4 vv = *(const float4*)(v + (size_t)(tok0 + row) * SH + head * HD + c);
        Vt[(c + 0) * 72 + row] = f2bf(vv.x);
        Vt[(c + 1) * 72 + row] = f2bf(vv.y);
        Vt[(c + 2) * 72 + row] = f2bf(vv.z);
        Vt[(c + 3) * 72 + row] = f2bf(vv.w);
    }
    __syncthreads();

    const int wave = tid >> 6;
    const int lane = tid & 63;
    const int l15  = lane & 15;
    const int lg   = lane >> 4;

    // ---- scores: S = Qr * Kr^T (split precision: hh + hl + lh) ----
    f32x4 accS[4] = {{0,0,0,0},{0,0,0,0},{0,0,0,0},{0,0,0,0}};
    const int arow = (wave * 16 + l15) * 104;
    #pragma unroll
    for (int st = 0; st < 3; ++st) {
        const int ko = st * 32 + lg * 8;
        const short8 ah = *(const short8*)&Qh[arow + ko];
        const short8 al = *(const short8*)&Ql[arow + ko];
        #pragma unroll
        for (int t = 0; t < 4; ++t) {
            const int brow = (t * 16 + l15) * 104 + ko;
            const short8 bh = *(const short8*)&Kh[brow];
            const short8 bl = *(const short8*)&Kl[brow];
            accS[t] = __builtin_amdgcn_mfma_f32_16x16x32_bf16(ah, bh, accS[t], 0, 0, 0);
            accS[t] = __builtin_amdgcn_mfma_f32_16x16x32_bf16(ah, bl, accS[t], 0, 0, 0);
            accS[t] = __builtin_amdgcn_mfma_f32_16x16x32_bf16(al, bh, accS[t], 0, 0, 0);
        }
    }

    // ---- softmax over the 64 columns of each row ----
    const float scale = 0.11180339887498949f;  // 1/sqrt(80)
    #pragma unroll
    for (int reg = 0; reg < 4; ++reg) {
        float m = fmaxf(fmaxf(accS[0][reg], accS[1][reg]),
                        fmaxf(accS[2][reg], accS[3][reg]));
        #pragma unroll
        for (int msk = 8; msk; msk >>= 1) m = fmaxf(m, __shfl_xor(m, msk));
        float p[4]; float sum = 0.f;
        #pragma unroll
        for (int t = 0; t < 4; ++t) { p[t] = __expf((accS[t][reg] - m) * scale); sum += p[t]; }
        #pragma unroll
        for (int msk = 8; msk; msk >>= 1) sum += __shfl_xor(sum, msk);
        const float inv = 1.f / sum;
        const int prow = (wave * 16 + lg * 4 + reg) * 72;
        #pragma unroll
        for (int t = 0; t < 4; ++t) Ps[prow + t * 16 + l15] = f2bf(p[t] * inv);
    }
    __syncthreads();

    // ---- O = P * V ----
    f32x4 accO[5] = {{0,0,0,0},{0,0,0,0},{0,0,0,0},{0,0,0,0},{0,0,0,0}};
    const int parow = (wave * 16 + l15) * 72;
    #pragma unroll
    for (int st = 0; st < 2; ++st) {
        const int ko = st * 32 + lg * 8;
        const short8 pf = *(const short8*)&Ps[parow + ko];
        #pragma unroll
        for (int t = 0; t < 5; ++t) {
            const short8 vf = *(const short8*)&Vt[(t * 16 + l15) * 72 + ko];
            accO[t] = __builtin_amdgcn_mfma_f32_16x16x32_bf16(pf, vf, accO[t], 0, 0, 0);
        }
    }

    // ---- write out (f32) ----
    const int orow = tok0 + wave * 16 + lg * 4;
    #pragma unroll
    for (int t = 0; t < 5; ++t) {
        #pragma unroll
        for (int r = 0; r < 4; ++r) {
            out[(size_t)(orow + r) * SH + head * HD + t * 16 + l15] = accO[t][r];
        }
    }
}

extern "C" void kernel_launch(void* const* d_in, const int* in_sizes, int n_in,
                              void* d_out, int out_size, void* d_ws, size_t ws_size,
                              hipStream_t stream) {
    const float* q    = (const float*)d_in[0];
    const float* k    = (const float*)d_in[1];
    const float* v    = (const float*)d_in[2];
    const float* cosb = (const float*)d_in[3];
    const float* sinb = (const float*)d_in[4];
    float* out = (float*)d_out;
    win_attn<<<dim3(8192), dim3(256), 0, stream>>>(q, k, v, cosb, sinb, out);
}

// Round 3
// 498.663 us; speedup vs baseline: 1.0602x; 1.0602x over previous
//
#include <hip/hip_runtime.h>

typedef __attribute__((ext_vector_type(8))) short short8;
typedef __attribute__((ext_vector_type(4))) float f32x4;

#define NH 16
#define HD 80
#define SH (NH*HD)
#define WIN 64

__device__ __forceinline__ unsigned short f2bf(float x) {
    union { float f; unsigned int u; } c; c.f = x;
    unsigned int u = c.u;
    u = (u + 0x7FFFu + ((u >> 16) & 1u)) >> 16;
    return (unsigned short)u;
}
__device__ __forceinline__ float bf2f(unsigned short h) {
    union { unsigned int u; float f; } c; c.u = ((unsigned int)h) << 16;
    return c.f;
}

__global__ __launch_bounds__(256, 4) void win_attn(
    const float* __restrict__ q, const float* __restrict__ k,
    const float* __restrict__ v, const float* __restrict__ cosb,
    const float* __restrict__ sinb, float* __restrict__ out)
{
    // 39,936 B total -> 4 blocks/CU.
    // Phase 1 (scores): Qh | Kh | Kl   (each 64 rows x stride 104, d padded to 96)
    // Phase 2 (PV):     Ps (over Qh, 64x72) | Vt (over Kl, 80x72)
    __shared__ unsigned short sm[19968];
    unsigned short* const Qh = sm;              // 6656 shorts
    unsigned short* const Kh = sm + 6656;       // 6656 shorts
    unsigned short* const Kl = sm + 13312;      // 6656 shorts
    unsigned short* const Ps = sm;              // 4608 shorts (aliases Qh)
    unsigned short* const Vt = sm + 13312;      // 5760 shorts (aliases Kl)

    const int head = blockIdx.x & (NH - 1);
    const int win  = blockIdx.x >> 4;
    const int tid  = threadIdx.x;
    const int tok0 = win * WIN;

    // ---- issue V loads early; hold in regs until after scores (T14) ----
    float4 vreg[5];
    #pragma unroll
    for (int j = 0; j < 5; ++j) {
        const int idx = tid + 256 * j;          // 1280 float4s total
        const int row = idx / 20;
        const int c   = (idx % 20) * 4;
        vreg[j] = *(const float4*)(v + (size_t)(tok0 + row) * SH + head * HD + c);
    }

    // ---- load + RoPE Q,K -> LDS (Q: hi only; K: hi/lo split) ----
    for (int idx = tid; idx < 640; idx += 256) {
        const int row = idx / 10;
        const int c0  = (idx % 10) * 4;          // column within first half (0..36)
        const size_t goff = (size_t)(tok0 + row) * SH + head * HD + c0;
        const float4 qa = *(const float4*)(q + goff);
        const float4 qb = *(const float4*)(q + goff + 40);
        const float4 ka = *(const float4*)(k + goff);
        const float4 kb = *(const float4*)(k + goff + 40);
        const size_t coff = (size_t)(tok0 + row) * 40 + c0;
        const float4 cc = *(const float4*)(cosb + coff);
        const float4 ss = *(const float4*)(sinb + coff);
        const int o0 = row * 104 + c0;
        #pragma unroll
        for (int i = 0; i < 4; ++i) {
            const float ci = ((const float*)&cc)[i], si = ((const float*)&ss)[i];
            const float q0 = ((const float*)&qa)[i], q1 = ((const float*)&qb)[i];
            const float k0 = ((const float*)&ka)[i], k1 = ((const float*)&kb)[i];
            const float qr0 = q0 * ci - q1 * si, qr1 = q0 * si + q1 * ci;
            const float kr0 = k0 * ci - k1 * si, kr1 = k0 * si + k1 * ci;
            Qh[o0 + i]      = f2bf(qr0);
            Qh[o0 + 40 + i] = f2bf(qr1);
            unsigned short h;
            h = f2bf(kr0); Kh[o0 + i]      = h; Kl[o0 + i]      = f2bf(kr0 - bf2f(h));
            h = f2bf(kr1); Kh[o0 + 40 + i] = h; Kl[o0 + 40 + i] = f2bf(kr1 - bf2f(h));
        }
    }
    // zero-pad d in [80,96)
    for (int idx = tid; idx < 1024; idx += 256) {
        const int o = (idx >> 4) * 104 + 80 + (idx & 15);
        Qh[o] = 0; Kh[o] = 0; Kl[o] = 0;
    }
    __syncthreads();

    const int wave = tid >> 6;
    const int lane = tid & 63;
    const int l15  = lane & 15;
    const int lg   = lane >> 4;

    // ---- scores: S = Qh * (Kh + Kl)^T ----
    f32x4 accS[4] = {{0,0,0,0},{0,0,0,0},{0,0,0,0},{0,0,0,0}};
    const int arow = (wave * 16 + l15) * 104;
    #pragma unroll
    for (int st = 0; st < 3; ++st) {
        const int ko = st * 32 + lg * 8;
        const short8 ah = *(const short8*)&Qh[arow + ko];
        #pragma unroll
        for (int t = 0; t < 4; ++t) {
            const int brow = (t * 16 + l15) * 104 + ko;
            const short8 bh = *(const short8*)&Kh[brow];
            const short8 bl = *(const short8*)&Kl[brow];
            accS[t] = __builtin_amdgcn_mfma_f32_16x16x32_bf16(ah, bh, accS[t], 0, 0, 0);
            accS[t] = __builtin_amdgcn_mfma_f32_16x16x32_bf16(ah, bl, accS[t], 0, 0, 0);
        }
    }
    __syncthreads();   // Qh/Kl dead; safe to overwrite with Ps/Vt

    // ---- V regs -> Vt (transposed [d][key], stride 72) ----
    #pragma unroll
    for (int j = 0; j < 5; ++j) {
        const int idx = tid + 256 * j;
        const int row = idx / 20;
        const int c   = (idx % 20) * 4;
        Vt[(c + 0) * 72 + row] = f2bf(vreg[j].x);
        Vt[(c + 1) * 72 + row] = f2bf(vreg[j].y);
        Vt[(c + 2) * 72 + row] = f2bf(vreg[j].z);
        Vt[(c + 3) * 72 + row] = f2bf(vreg[j].w);
    }

    // ---- softmax over the 64 columns of each row -> Ps ----
    const float scale = 0.11180339887498949f;  // 1/sqrt(80)
    #pragma unroll
    for (int reg = 0; reg < 4; ++reg) {
        float m = fmaxf(fmaxf(accS[0][reg], accS[1][reg]),
                        fmaxf(accS[2][reg], accS[3][reg]));
        #pragma unroll
        for (int msk = 8; msk; msk >>= 1) m = fmaxf(m, __shfl_xor(m, msk));
        float p[4]; float sum = 0.f;
        #pragma unroll
        for (int t = 0; t < 4; ++t) { p[t] = __expf((accS[t][reg] - m) * scale); sum += p[t]; }
        #pragma unroll
        for (int msk = 8; msk; msk >>= 1) sum += __shfl_xor(sum, msk);
        const float inv = 1.f / sum;
        const int prow = (wave * 16 + lg * 4 + reg) * 72;
        #pragma unroll
        for (int t = 0; t < 4; ++t) Ps[prow + t * 16 + l15] = f2bf(p[t] * inv);
    }
    __syncthreads();

    // ---- O = P * V ----
    f32x4 accO[5] = {{0,0,0,0},{0,0,0,0},{0,0,0,0},{0,0,0,0},{0,0,0,0}};
    const int parow = (wave * 16 + l15) * 72;
    #pragma unroll
    for (int st = 0; st < 2; ++st) {
        const int ko = st * 32 + lg * 8;
        const short8 pf = *(const short8*)&Ps[parow + ko];
        #pragma unroll
        for (int t = 0; t < 5; ++t) {
            const short8 vf = *(const short8*)&Vt[(t * 16 + l15) * 72 + ko];
            accO[t] = __builtin_amdgcn_mfma_f32_16x16x32_bf16(pf, vf, accO[t], 0, 0, 0);
        }
    }

    // ---- write out (f32) ----
    const int orow = tok0 + wave * 16 + lg * 4;
    #pragma unroll
    for (int t = 0; t < 5; ++t) {
        #pragma unroll
        for (int r = 0; r < 4; ++r) {
            out[(size_t)(orow + r) * SH + head * HD + t * 16 + l15] = accO[t][r];
        }
    }
}

extern "C" void kernel_launch(void* const* d_in, const int* in_sizes, int n_in,
                              void* d_out, int out_size, void* d_ws, size_t ws_size,
                              hipStream_t stream) {
    const float* q    = (const float*)d_in[0];
    const float* k    = (const float*)d_in[1];
    const float* v    = (const float*)d_in[2];
    const float* cosb = (const float*)d_in[3];
    const float* sinb = (const float*)d_in[4];
    float* out = (float*)d_out;
    win_attn<<<dim3(8192), dim3(256), 0, stream>>>(q, k, v, cosb, sinb, out);
}